// Round 2
// baseline (479.088 us; speedup 1.0000x reference)
//
#include <hip/hip_runtime.h>

#define BB 4
#define NN 100000
#define KK 16
#define DD 6
#define FF 13
#define LL 3
#define NPTS (BB * NN)
#define EPS 1e-5f
#define SLOPE 0.2f

// 16 lanes per point: lane k handles neighbor k.
// Input per thread: 6 atomtypes + 1 dist, held in registers across all 3 layers.
// msg reduced across the 16-lane group via shfl_xor; groupnorm + pe update
// computed redundantly in all 16 lanes (keeps pe lane-resident, no broadcast).
__global__ __launch_bounds__(256) void atom_mp_kernel(
    const float* __restrict__ dist,      // [B,N,K,1]
    const float* __restrict__ atomtypes, // [B,N,K,D]
    const float* __restrict__ w1,        // [L,F,F]
    const float* __restrict__ b1,        // [L,F]
    const float* __restrict__ w2,        // [L,F,D]
    const float* __restrict__ b2,        // [L,D]
    const float* __restrict__ gnw,       // [L,D]
    const float* __restrict__ gnb,       // [L,D]
    float* __restrict__ out)             // [B,N,D]
{
    __shared__ float s_w1[LL * FF * FF];   // 507
    __shared__ float s_b1[LL * FF];        // 39
    __shared__ float s_w2[LL * FF * DD];   // 234
    __shared__ float s_b2[LL * DD];        // 18
    __shared__ float s_gnw[LL * DD];
    __shared__ float s_gnb[LL * DD];

    for (int i = threadIdx.x; i < LL * FF * FF; i += blockDim.x) s_w1[i] = w1[i];
    for (int i = threadIdx.x; i < LL * FF;      i += blockDim.x) s_b1[i] = b1[i];
    for (int i = threadIdx.x; i < LL * FF * DD; i += blockDim.x) s_w2[i] = w2[i];
    for (int i = threadIdx.x; i < LL * DD;      i += blockDim.x) {
        s_b2[i]  = b2[i];
        s_gnw[i] = gnw[i];
        s_gnb[i] = gnb[i];
    }
    __syncthreads();

    // global thread t: point p = t>>4, neighbor k = t&15
    const int t = blockIdx.x * blockDim.x + threadIdx.x;  // grid sized exactly

    // coalesced: consecutive lanes read consecutive 24B chunks
    const float2 a01 = *reinterpret_cast<const float2*>(atomtypes + (size_t)t * DD + 0);
    const float2 a23 = *reinterpret_cast<const float2*>(atomtypes + (size_t)t * DD + 2);
    const float2 a45 = *reinterpret_cast<const float2*>(atomtypes + (size_t)t * DD + 4);
    const float dk = dist[t];
    float at[DD];
    at[0] = a01.x; at[1] = a01.y;
    at[2] = a23.x; at[3] = a23.y;
    at[4] = a45.x; at[5] = a45.y;

    float pe[DD];
    #pragma unroll
    for (int d = 0; d < DD; ++d) pe[d] = 1.0f;

    #pragma unroll
    for (int l = 0; l < LL; ++l) {
        const float* __restrict__ lw1 = s_w1 + l * FF * FF;
        const float* __restrict__ lb1 = s_b1 + l * FF;
        const float* __restrict__ lw2 = s_w2 + l * FF * DD;
        const float* __restrict__ lb2 = s_b2 + l * DD;

        // h[j] = b1[j] + sum_d pe[d]*w1[d][j] + sum_d at[d]*w1[6+d][j] + dk*w1[12][j]
        float h[FF];
        #pragma unroll
        for (int j = 0; j < FF; ++j) h[j] = lb1[j];
        #pragma unroll
        for (int d = 0; d < DD; ++d) {
            const float x = pe[d];
            #pragma unroll
            for (int j = 0; j < FF; ++j) h[j] = fmaf(x, lw1[d * FF + j], h[j]);
        }
        #pragma unroll
        for (int d = 0; d < DD; ++d) {
            const float x = at[d];
            #pragma unroll
            for (int j = 0; j < FF; ++j) h[j] = fmaf(x, lw1[(DD + d) * FF + j], h[j]);
        }
        #pragma unroll
        for (int j = 0; j < FF; ++j) h[j] = fmaf(dk, lw1[(2 * DD) * FF + j], h[j]);

        #pragma unroll
        for (int j = 0; j < FF; ++j) h[j] = h[j] > 0.0f ? h[j] : SLOPE * h[j];

        // partial msg for this k
        float msg[DD];
        #pragma unroll
        for (int d = 0; d < DD; ++d) msg[d] = 0.0f;
        #pragma unroll
        for (int j = 0; j < FF; ++j) {
            const float x = h[j];
            #pragma unroll
            for (int d = 0; d < DD; ++d) msg[d] = fmaf(x, lw2[j * DD + d], msg[d]);
        }

        // reduce over the 16 lanes of this point (xor masks < 16 stay in-group)
        #pragma unroll
        for (int m = 1; m < KK; m <<= 1) {
            #pragma unroll
            for (int d = 0; d < DD; ++d) msg[d] += __shfl_xor(msg[d], m);
        }
        #pragma unroll
        for (int d = 0; d < DD; ++d) msg[d] += (float)KK * lb2[d];

        // GroupNorm (2 groups of 3) + leaky + residual, redundantly in all lanes
        #pragma unroll
        for (int g = 0; g < 2; ++g) {
            const float m0 = msg[g * 3 + 0];
            const float m1 = msg[g * 3 + 1];
            const float m2 = msg[g * 3 + 2];
            const float mu = (m0 + m1 + m2) * (1.0f / 3.0f);
            const float d0 = m0 - mu, d1 = m1 - mu, d2 = m2 - mu;
            const float var = (d0 * d0 + d1 * d1 + d2 * d2) * (1.0f / 3.0f);
            const float rs = rsqrtf(var + EPS);
            #pragma unroll
            for (int c = 0; c < 3; ++c) {
                const float dd = (c == 0 ? d0 : (c == 1 ? d1 : d2));
                float x = fmaf(dd * rs, s_gnw[l * DD + g * 3 + c], s_gnb[l * DD + g * 3 + c]);
                x = x > 0.0f ? x : SLOPE * x;
                pe[g * 3 + c] += x;
            }
        }
    }

    // lane k==0 of each point writes the 6 outputs
    if ((t & (KK - 1)) == 0) {
        const int p = t >> 4;
        float* __restrict__ op = out + (size_t)p * DD;
        *reinterpret_cast<float2*>(op + 0) = make_float2(pe[0], pe[1]);
        *reinterpret_cast<float2*>(op + 2) = make_float2(pe[2], pe[3]);
        *reinterpret_cast<float2*>(op + 4) = make_float2(pe[4], pe[5]);
    }
}

extern "C" void kernel_launch(void* const* d_in, const int* in_sizes, int n_in,
                              void* d_out, int out_size, void* d_ws, size_t ws_size,
                              hipStream_t stream) {
    const float* dist      = (const float*)d_in[0];
    const float* atomtypes = (const float*)d_in[1];
    const float* w1        = (const float*)d_in[2];
    const float* b1        = (const float*)d_in[3];
    const float* w2        = (const float*)d_in[4];
    const float* b2        = (const float*)d_in[5];
    const float* gnw       = (const float*)d_in[6];
    const float* gnb       = (const float*)d_in[7];
    float* out             = (float*)d_out;

    const int threads = 256;
    const int total = NPTS * KK;                 // 6,400,000 (exact multiple of 256)
    const int blocks = total / threads;          // 25,000
    atom_mp_kernel<<<blocks, threads, 0, stream>>>(dist, atomtypes, w1, b1, w2, b2,
                                                   gnw, gnb, out);
}

// Round 3
// 412.113 us; speedup vs baseline: 1.1625x; 1.1625x over previous
//
#include <hip/hip_runtime.h>

#define BB 4
#define NN 100000
#define KK 16
#define DD 6
#define FF 13
#define LL 3
#define NPTS (BB * NN)
#define EPS 1e-5f
#define SLOPE 0.2f

// One thread per point. Weights read straight from GLOBAL memory with
// wave-uniform indices -> compiler emits s_load into SGPRs (scalar cache),
// and each v_fma uses the weight as its single SGPR operand. No LDS at all
// (R0/R1 were ds_read-throughput-bound on LDS weight streaming).
__global__ __launch_bounds__(256, 4) void atom_mp_kernel(
    const float* __restrict__ dist,      // [B,N,K,1]
    const float* __restrict__ atomtypes, // [B,N,K,D]
    const float* __restrict__ w1,        // [L,F,F]
    const float* __restrict__ b1,        // [L,F]
    const float* __restrict__ w2,        // [L,F,D]
    const float* __restrict__ b2,        // [L,D]
    const float* __restrict__ gnw,       // [L,D]
    const float* __restrict__ gnb,       // [L,D]
    float* __restrict__ out)             // [B,N,D]
{
    const int p = blockIdx.x * blockDim.x + threadIdx.x;
    if (p >= NPTS) return;

    // per-point input rows: 16 neighbors x 6 floats (384B, 16B-aligned),
    // 16 dists (64B, 16B-aligned)
    const float4* __restrict__ at4 = reinterpret_cast<const float4*>(
        atomtypes + (size_t)p * (KK * DD));
    const float2* __restrict__ dp2 = reinterpret_cast<const float2*>(
        dist + (size_t)p * KK);

    float pe[DD];
    #pragma unroll
    for (int d = 0; d < DD; ++d) pe[d] = 1.0f;

    #pragma unroll 1   // keep code size within I-cache; body identical per layer
    for (int l = 0; l < LL; ++l) {
        const float* __restrict__ lw1 = w1 + l * FF * FF;   // uniform -> s_load
        const float* __restrict__ lb1 = b1 + l * FF;
        const float* __restrict__ lw2 = w2 + l * FF * DD;
        const float* __restrict__ lb2 = b2 + l * DD;

        // base[j] = b1[j] + sum_d pe[d] * w1[d][j]  (k-invariant part)
        float base[FF];
        #pragma unroll
        for (int j = 0; j < FF; ++j) base[j] = lb1[j];
        #pragma unroll
        for (int d = 0; d < DD; ++d) {
            const float x = pe[d];
            #pragma unroll
            for (int j = 0; j < FF; ++j) base[j] = fmaf(x, lw1[d * FF + j], base[j]);
        }

        float msg[DD];
        #pragma unroll
        for (int d = 0; d < DD; ++d) msg[d] = (float)KK * lb2[d];

        // one neighbor: h = leaky(base + at*W1b + dk*W1c); msg += h @ W2
        auto doK = [&](float x0, float x1, float x2, float x3, float x4, float x5,
                       float dk) {
            float xs[DD] = {x0, x1, x2, x3, x4, x5};  // unrolled -> static indices
            float h[FF];
            #pragma unroll
            for (int j = 0; j < FF; ++j) h[j] = base[j];
            #pragma unroll
            for (int d = 0; d < DD; ++d) {
                #pragma unroll
                for (int j = 0; j < FF; ++j)
                    h[j] = fmaf(xs[d], lw1[(DD + d) * FF + j], h[j]);
            }
            #pragma unroll
            for (int j = 0; j < FF; ++j)
                h[j] = fmaf(dk, lw1[2 * DD * FF + j], h[j]);
            #pragma unroll
            for (int j = 0; j < FF; ++j) h[j] = h[j] > 0.0f ? h[j] : SLOPE * h[j];
            #pragma unroll
            for (int j = 0; j < FF; ++j) {
                const float x = h[j];
                #pragma unroll
                for (int d = 0; d < DD; ++d)
                    msg[d] = fmaf(x, lw2[j * DD + d], msg[d]);
            }
        };

        // neighbors in pairs: 12 floats = 3x dwordx4, dists 2 = 1x dwordx2
        #pragma unroll 2
        for (int m = 0; m < KK / 2; ++m) {
            const float4 a0 = at4[3 * m + 0];
            const float4 a1 = at4[3 * m + 1];
            const float4 a2 = at4[3 * m + 2];
            const float2 dm = dp2[m];
            doK(a0.x, a0.y, a0.z, a0.w, a1.x, a1.y, dm.x);
            doK(a1.z, a1.w, a2.x, a2.y, a2.z, a2.w, dm.y);
        }

        // GroupNorm (2 groups of 3, biased var) + leaky + residual
        #pragma unroll
        for (int g = 0; g < 2; ++g) {
            const float m0 = msg[g * 3 + 0];
            const float m1 = msg[g * 3 + 1];
            const float m2 = msg[g * 3 + 2];
            const float mu = (m0 + m1 + m2) * (1.0f / 3.0f);
            const float d0 = m0 - mu, d1 = m1 - mu, d2 = m2 - mu;
            const float var = (d0 * d0 + d1 * d1 + d2 * d2) * (1.0f / 3.0f);
            const float rs = rsqrtf(var + EPS);
            #pragma unroll
            for (int c = 0; c < 3; ++c) {
                const float dd = (c == 0 ? d0 : (c == 1 ? d1 : d2));
                float x = fmaf(dd * rs, gnw[l * DD + g * 3 + c],
                               gnb[l * DD + g * 3 + c]);
                x = x > 0.0f ? x : SLOPE * x;
                pe[g * 3 + c] += x;
            }
        }
    }

    float* __restrict__ op = out + (size_t)p * DD;
    *reinterpret_cast<float2*>(op + 0) = make_float2(pe[0], pe[1]);
    *reinterpret_cast<float2*>(op + 2) = make_float2(pe[2], pe[3]);
    *reinterpret_cast<float2*>(op + 4) = make_float2(pe[4], pe[5]);
}

extern "C" void kernel_launch(void* const* d_in, const int* in_sizes, int n_in,
                              void* d_out, int out_size, void* d_ws, size_t ws_size,
                              hipStream_t stream) {
    const float* dist      = (const float*)d_in[0];
    const float* atomtypes = (const float*)d_in[1];
    const float* w1        = (const float*)d_in[2];
    const float* b1        = (const float*)d_in[3];
    const float* w2        = (const float*)d_in[4];
    const float* b2        = (const float*)d_in[5];
    const float* gnw       = (const float*)d_in[6];
    const float* gnb       = (const float*)d_in[7];
    float* out             = (float*)d_out;

    const int threads = 256;
    const int blocks = (NPTS + threads - 1) / threads;
    atom_mp_kernel<<<blocks, threads, 0, stream>>>(dist, atomtypes, w1, b1, w2, b2,
                                                   gnw, gnb, out);
}

// Round 4
// 387.131 us; speedup vs baseline: 1.2375x; 1.0645x over previous
//
#include <hip/hip_runtime.h>

#define BB 4
#define NN 100000
#define KK 16
#define DD 6
#define FF 13
#define LL 3
#define NPTS (BB * NN)
#define EPS 1e-5f
#define SLOPE 0.2f

// 4 lanes per point; lane q handles neighbors 4q..4q+3.
// All neighbor features (24 floats) + dists (4) loaded ONCE into registers and
// reused across all 3 layers -> single HBM pass. Weights via wave-uniform
// global reads (scalar cache). msg reduced with 2 shfl_xor steps; base/GN
// computed redundantly in the 4 lanes (keeps pe lane-resident).
__global__ __launch_bounds__(256) void atom_mp_kernel(
    const float* __restrict__ dist,      // [B,N,K,1]
    const float* __restrict__ atomtypes, // [B,N,K,D]
    const float* __restrict__ w1,        // [L,F,F]
    const float* __restrict__ b1,        // [L,F]
    const float* __restrict__ w2,        // [L,F,D]
    const float* __restrict__ b2,        // [L,D]
    const float* __restrict__ gnw,       // [L,D]
    const float* __restrict__ gnb,       // [L,D]
    float* __restrict__ out)             // [B,N,D]
{
    const int t = blockIdx.x * blockDim.x + threadIdx.x;   // 1.6M threads exact
    const int p = t >> 2;        // point
    const int q4 = t & 3;        // which 4-neighbor group

    // Load this lane's 4 neighbor rows (24 floats, 96B, 16B-aligned) + 4 dists.
    const float4* __restrict__ a4 = reinterpret_cast<const float4*>(
        atomtypes + (size_t)p * (KK * DD) + q4 * (4 * DD));
    const float4 v0 = a4[0], v1 = a4[1], v2 = a4[2],
                 v3 = a4[3], v4 = a4[4], v5 = a4[5];
    const float4 dv = *reinterpret_cast<const float4*>(
        dist + (size_t)p * KK + q4 * 4);

    float at[4][DD];
    at[0][0] = v0.x; at[0][1] = v0.y; at[0][2] = v0.z; at[0][3] = v0.w;
    at[0][4] = v1.x; at[0][5] = v1.y;
    at[1][0] = v1.z; at[1][1] = v1.w; at[1][2] = v2.x; at[1][3] = v2.y;
    at[1][4] = v2.z; at[1][5] = v2.w;
    at[2][0] = v3.x; at[2][1] = v3.y; at[2][2] = v3.z; at[2][3] = v3.w;
    at[2][4] = v4.x; at[2][5] = v4.y;
    at[3][0] = v4.z; at[3][1] = v4.w; at[3][2] = v5.x; at[3][3] = v5.y;
    at[3][4] = v5.z; at[3][5] = v5.w;
    float dk[4] = {dv.x, dv.y, dv.z, dv.w};

    float pe[DD];
    #pragma unroll
    for (int d = 0; d < DD; ++d) pe[d] = 1.0f;

    #pragma unroll 1
    for (int l = 0; l < LL; ++l) {
        const float* __restrict__ lw1 = w1 + l * FF * FF;   // uniform -> s_load
        const float* __restrict__ lb1 = b1 + l * FF;
        const float* __restrict__ lw2 = w2 + l * FF * DD;
        const float* __restrict__ lb2 = b2 + l * DD;

        // bse[j] = b1[j] + sum_d pe[d]*w1[d][j]   (k-invariant)
        float bse[FF];
        #pragma unroll
        for (int j = 0; j < FF; ++j) bse[j] = lb1[j];
        #pragma unroll
        for (int d = 0; d < DD; ++d) {
            const float x = pe[d];
            #pragma unroll
            for (int j = 0; j < FF; ++j) bse[j] = fmaf(x, lw1[d * FF + j], bse[j]);
        }

        float msg[DD];
        #pragma unroll
        for (int d = 0; d < DD; ++d) msg[d] = 0.0f;

        #pragma unroll
        for (int k = 0; k < 4; ++k) {
            float h[FF];
            #pragma unroll
            for (int j = 0; j < FF; ++j) h[j] = bse[j];
            #pragma unroll
            for (int d = 0; d < DD; ++d) {
                const float x = at[k][d];
                #pragma unroll
                for (int j = 0; j < FF; ++j)
                    h[j] = fmaf(x, lw1[(DD + d) * FF + j], h[j]);
            }
            const float xd = dk[k];
            #pragma unroll
            for (int j = 0; j < FF; ++j)
                h[j] = fmaf(xd, lw1[2 * DD * FF + j], h[j]);
            // leaky relu, slope<1: max(x, slope*x) = 2 inst
            #pragma unroll
            for (int j = 0; j < FF; ++j) h[j] = fmaxf(h[j], SLOPE * h[j]);
            #pragma unroll
            for (int j = 0; j < FF; ++j) {
                const float x = h[j];
                #pragma unroll
                for (int d = 0; d < DD; ++d)
                    msg[d] = fmaf(x, lw2[j * DD + d], msg[d]);
            }
        }

        // reduce partial msg across the 4 lanes of this point
        #pragma unroll
        for (int d = 0; d < DD; ++d) msg[d] += __shfl_xor(msg[d], 1);
        #pragma unroll
        for (int d = 0; d < DD; ++d) msg[d] += __shfl_xor(msg[d], 2);
        #pragma unroll
        for (int d = 0; d < DD; ++d) msg[d] += (float)KK * lb2[d];

        // GroupNorm (2 groups of 3, biased var) + leaky + residual (all lanes)
        #pragma unroll
        for (int g = 0; g < 2; ++g) {
            const float m0 = msg[g * 3 + 0];
            const float m1 = msg[g * 3 + 1];
            const float m2 = msg[g * 3 + 2];
            const float mu = (m0 + m1 + m2) * (1.0f / 3.0f);
            const float d0 = m0 - mu, d1 = m1 - mu, d2 = m2 - mu;
            const float var = (d0 * d0 + d1 * d1 + d2 * d2) * (1.0f / 3.0f);
            const float rs = rsqrtf(var + EPS);
            #pragma unroll
            for (int c = 0; c < 3; ++c) {
                const float dd = (c == 0 ? d0 : (c == 1 ? d1 : d2));
                float x = fmaf(dd * rs, gnw[l * DD + g * 3 + c],
                               gnb[l * DD + g * 3 + c]);
                x = fmaxf(x, SLOPE * x);
                pe[g * 3 + c] += x;
            }
        }
    }

    if (q4 == 0) {
        float* __restrict__ op = out + (size_t)p * DD;
        *reinterpret_cast<float2*>(op + 0) = make_float2(pe[0], pe[1]);
        *reinterpret_cast<float2*>(op + 2) = make_float2(pe[2], pe[3]);
        *reinterpret_cast<float2*>(op + 4) = make_float2(pe[4], pe[5]);
    }
}

extern "C" void kernel_launch(void* const* d_in, const int* in_sizes, int n_in,
                              void* d_out, int out_size, void* d_ws, size_t ws_size,
                              hipStream_t stream) {
    const float* dist      = (const float*)d_in[0];
    const float* atomtypes = (const float*)d_in[1];
    const float* w1        = (const float*)d_in[2];
    const float* b1        = (const float*)d_in[3];
    const float* w2        = (const float*)d_in[4];
    const float* b2        = (const float*)d_in[5];
    const float* gnw       = (const float*)d_in[6];
    const float* gnb       = (const float*)d_in[7];
    float* out             = (float*)d_out;

    const int threads = 256;
    const int total = NPTS * 4;              // 1,600,000 (multiple of 256)
    const int blocks = total / threads;      // 6250
    atom_mp_kernel<<<blocks, threads, 0, stream>>>(dist, atomtypes, w1, b1, w2, b2,
                                                   gnw, gnb, out);
}

// Round 6
// 283.903 us; speedup vs baseline: 1.6875x; 1.3636x over previous
//
#include <hip/hip_runtime.h>

#define BB 4
#define NN 100000
#define KK 16
#define DD 6
#define FF 13
#define LL 3
#define NPTS (BB * NN)
#define EPS 1e-5f
#define SLOPE 0.2f

typedef _Float16 half2v __attribute__((ext_vector_type(2)));

// d_ws layout (dwords):
//   [0, 273)    w1pk  [L][7][13] half2 : pair t of input features, col j
//   [273, 399)  w2pk  [L][7][6]  half2 : pair t of hidden feats, out d
//   [399, 438)  b1    [L][13] f32
//   [438, 456)  b2    [L][6]  f32
//   [456, 474)  gnw   [L][6]  f32
//   [474, 492)  gnb   [L][6]  f32
#define WS_W2PK 273
#define WS_B1   399
#define WS_B2   438
#define WS_GNW  456
#define WS_GNB  474
#define WS_TOT  492

__device__ __forceinline__ float dot2(half2v a, half2v b, float c) {
#if __has_builtin(__builtin_amdgcn_fdot2)
    return __builtin_amdgcn_fdot2(a, b, c, false);
#else
    return fmaf((float)a.x, (float)b.x, fmaf((float)a.y, (float)b.y, c));
#endif
}

__device__ __forceinline__ half2v pk(float x, float y) {
#if __has_builtin(__builtin_amdgcn_cvt_pkrtz)
    auto r = __builtin_amdgcn_cvt_pkrtz(x, y);   // __fp16 vec2 — same bits
    union { decltype(r) a; half2v b; } c; c.a = r; return c.b;
#else
    half2v r; r.x = (_Float16)x; r.y = (_Float16)y; return r;
#endif
}

__device__ __forceinline__ unsigned h2u(half2v h) {
    union { half2v h; unsigned u; } c; c.h = h; return c.u;
}

__global__ void prep_weights(const float* __restrict__ w1,
                             const float* __restrict__ b1,
                             const float* __restrict__ w2,
                             const float* __restrict__ b2,
                             const float* __restrict__ gnw,
                             const float* __restrict__ gnb,
                             unsigned* __restrict__ ws) {
    const int i = threadIdx.x;   // one block of 512 covers 492
    if (i < 273) {               // w1pk: i = l*91 + t*13 + j
        const int l = i / 91, r = i % 91, t = r / 13, j = r % 13;
        const float a = w1[l * 169 + (2 * t) * 13 + j];
        const float b = (t < 6) ? w1[l * 169 + (2 * t + 1) * 13 + j] : 0.0f;
        half2v h; h.x = (_Float16)a; h.y = (_Float16)b;
        ws[i] = h2u(h);
    } else if (i < 399) {        // w2pk: m = l*42 + t*6 + d
        const int m = i - 273;
        const int l = m / 42, r = m % 42, t = r / 6, d = r % 6;
        const float a = w2[l * 78 + (2 * t) * 6 + d];
        const float b = (t < 6) ? w2[l * 78 + (2 * t + 1) * 6 + d] : 0.0f;
        half2v h; h.x = (_Float16)a; h.y = (_Float16)b;
        ws[i] = h2u(h);
    } else if (i < 438) {
        ((float*)ws)[i] = b1[i - WS_B1];
    } else if (i < 456) {
        ((float*)ws)[i] = b2[i - WS_B2];
    } else if (i < 474) {
        ((float*)ws)[i] = gnw[i - WS_GNW];
    } else if (i < 492) {
        ((float*)ws)[i] = gnb[i - WS_GNB];
    }
}

// 4 lanes per point; lane q handles neighbors 4q..4q+3. Inputs packed to half2
// ONCE in registers; weights pre-packed half2 in ws (wave-uniform -> s_load,
// one sgpr = 2 weights). All dot products via v_dot2_f32_f16 (f32 accum).
__global__ __launch_bounds__(256, 4) void atom_mp_kernel(
    const float* __restrict__ dist,      // [B,N,K,1]
    const float* __restrict__ atomtypes, // [B,N,K,D]
    const unsigned* __restrict__ ws,
    float* __restrict__ out)             // [B,N,D]
{
    const int t = blockIdx.x * blockDim.x + threadIdx.x;
    const int p = t >> 2;
    const int q4 = t & 3;

    const half2v* __restrict__ w1pk = (const half2v*)ws;            // [L*91]
    const half2v* __restrict__ w2pk = (const half2v*)(ws + WS_W2PK);// [L*42]
    const float*  __restrict__ b1f  = (const float*)(ws + WS_B1);
    const float*  __restrict__ b2f  = (const float*)(ws + WS_B2);
    const float*  __restrict__ gnwf = (const float*)(ws + WS_GNW);
    const float*  __restrict__ gnbf = (const float*)(ws + WS_GNB);

    // load 4 neighbor rows (24 floats) + 4 dists, pack to half2
    const float4* __restrict__ a4 = reinterpret_cast<const float4*>(
        atomtypes + (size_t)p * (KK * DD) + q4 * (4 * DD));
    const float4 v0 = a4[0], v1 = a4[1], v2 = a4[2],
                 v3 = a4[3], v4 = a4[4], v5 = a4[5];
    const float4 dv = *reinterpret_cast<const float4*>(
        dist + (size_t)p * KK + q4 * 4);

    half2v atp[4][3];
    atp[0][0] = pk(v0.x, v0.y); atp[0][1] = pk(v0.z, v0.w); atp[0][2] = pk(v1.x, v1.y);
    atp[1][0] = pk(v1.z, v1.w); atp[1][1] = pk(v2.x, v2.y); atp[1][2] = pk(v2.z, v2.w);
    atp[2][0] = pk(v3.x, v3.y); atp[2][1] = pk(v3.z, v3.w); atp[2][2] = pk(v4.x, v4.y);
    atp[3][0] = pk(v4.z, v4.w); atp[3][1] = pk(v5.x, v5.y); atp[3][2] = pk(v5.z, v5.w);
    half2v dpk[4] = {pk(dv.x, 0.0f), pk(dv.y, 0.0f), pk(dv.z, 0.0f), pk(dv.w, 0.0f)};

    float pe[DD];
    #pragma unroll
    for (int d = 0; d < DD; ++d) pe[d] = 1.0f;

    #pragma unroll 1
    for (int l = 0; l < LL; ++l) {
        const half2v* __restrict__ lw1 = w1pk + l * 91;  // [t][j] t<7 j<13
        const half2v* __restrict__ lw2 = w2pk + l * 42;  // [t][d] t<7 d<6
        const float*  __restrict__ lb1 = b1f + l * FF;
        const float*  __restrict__ lb2 = b2f + l * DD;

        const half2v pe0 = pk(pe[0], pe[1]);
        const half2v pe1 = pk(pe[2], pe[3]);
        const half2v pe2 = pk(pe[4], pe[5]);

        // bse[j] = b1[j] + pe . W1[0:6, j]
        float bse[FF];
        #pragma unroll
        for (int j = 0; j < FF; ++j)
            bse[j] = dot2(pe0, lw1[0 * FF + j],
                     dot2(pe1, lw1[1 * FF + j],
                     dot2(pe2, lw1[2 * FF + j], lb1[j])));

        float msg[DD];
        #pragma unroll
        for (int d = 0; d < DD; ++d) msg[d] = 0.0f;

        #pragma unroll
        for (int k = 0; k < 4; ++k) {
            float h[FF];
            #pragma unroll
            for (int j = 0; j < FF; ++j) {
                float x = dot2(atp[k][0], lw1[3 * FF + j],
                          dot2(atp[k][1], lw1[4 * FF + j],
                          dot2(atp[k][2], lw1[5 * FF + j],
                          dot2(dpk[k],    lw1[6 * FF + j], bse[j]))));
                h[j] = fmaxf(x, SLOPE * x);   // leaky, slope<1
            }
            half2v hpk[7];
            #pragma unroll
            for (int u = 0; u < 6; ++u) hpk[u] = pk(h[2 * u], h[2 * u + 1]);
            hpk[6] = pk(h[12], 0.0f);
            #pragma unroll
            for (int d = 0; d < DD; ++d) {
                float m = msg[d];
                #pragma unroll
                for (int u = 0; u < 7; ++u) m = dot2(hpk[u], lw2[u * DD + d], m);
                msg[d] = m;
            }
        }

        // reduce partial msg across the 4 lanes of this point
        #pragma unroll
        for (int d = 0; d < DD; ++d) msg[d] += __shfl_xor(msg[d], 1);
        #pragma unroll
        for (int d = 0; d < DD; ++d) msg[d] += __shfl_xor(msg[d], 2);
        #pragma unroll
        for (int d = 0; d < DD; ++d) msg[d] += (float)KK * lb2[d];

        // GroupNorm (2 groups of 3, biased var) + leaky + residual
        #pragma unroll
        for (int g = 0; g < 2; ++g) {
            const float m0 = msg[g * 3 + 0];
            const float m1 = msg[g * 3 + 1];
            const float m2 = msg[g * 3 + 2];
            const float mu = (m0 + m1 + m2) * (1.0f / 3.0f);
            const float d0 = m0 - mu, d1 = m1 - mu, d2 = m2 - mu;
            const float var = (d0 * d0 + d1 * d1 + d2 * d2) * (1.0f / 3.0f);
            const float rs = rsqrtf(var + EPS);
            #pragma unroll
            for (int c = 0; c < 3; ++c) {
                const float dd = (c == 0 ? d0 : (c == 1 ? d1 : d2));
                float x = fmaf(dd * rs, gnwf[l * DD + g * 3 + c],
                               gnbf[l * DD + g * 3 + c]);
                x = fmaxf(x, SLOPE * x);
                pe[g * 3 + c] += x;
            }
        }
    }

    if (q4 == 0) {
        float* __restrict__ op = out + (size_t)p * DD;
        *reinterpret_cast<float2*>(op + 0) = make_float2(pe[0], pe[1]);
        *reinterpret_cast<float2*>(op + 2) = make_float2(pe[2], pe[3]);
        *reinterpret_cast<float2*>(op + 4) = make_float2(pe[4], pe[5]);
    }
}

extern "C" void kernel_launch(void* const* d_in, const int* in_sizes, int n_in,
                              void* d_out, int out_size, void* d_ws, size_t ws_size,
                              hipStream_t stream) {
    const float* dist      = (const float*)d_in[0];
    const float* atomtypes = (const float*)d_in[1];
    const float* w1        = (const float*)d_in[2];
    const float* b1        = (const float*)d_in[3];
    const float* w2        = (const float*)d_in[4];
    const float* b2        = (const float*)d_in[5];
    const float* gnw       = (const float*)d_in[6];
    const float* gnb       = (const float*)d_in[7];
    float* out             = (float*)d_out;
    unsigned* ws           = (unsigned*)d_ws;

    prep_weights<<<1, 512, 0, stream>>>(w1, b1, w2, b2, gnw, gnb, ws);

    const int threads = 256;
    const int total = NPTS * 4;              // 1,600,000
    const int blocks = total / threads;      // 6250
    atom_mp_kernel<<<blocks, threads, 0, stream>>>(dist, atomtypes, ws, out);
}